// Round 4
// baseline (146.457 us; speedup 1.0000x reference)
//
#include <hip/hip_runtime.h>
#include <hip/hip_bf16.h>
#include <math.h>

// QuantumFFN: out[m,n] = sum_k relu(sum_q cos(x[m,q])cos(theta[q]) * W1[k,q]) * W2[n,k]
// M=16384, N=1024, K=4096, Q=8.
//
// Pass 1 (k_prep): h (bf16) and W2 (bf16) -> d_ws, tiled [*, kt][256 rows][32 k], XOR-swizzled.
// Pass 2 (k_gemm): 256x256 bf16 MFMA GEMM, BK=32, 4-deep LDS ring, counted vmcnt,
//   register-prefetched fragments (reads for tile t+1 overlap MFMAs of tile t).

using f32x4  = __attribute__((ext_vector_type(4))) float;
using bf16x8 = __attribute__((ext_vector_type(8))) short;
using i32x4  = __attribute__((ext_vector_type(4))) int;

#define M_TOT 16384
#define N_TOT 1024
#define K_TOT 4096
#define NKT   128        // K-tiles of 32
#define TILEB 16384      // 256 rows x 32 k x 2B

static const size_t H_BYTES   = (size_t)M_TOT * K_TOT * 2;   // 128 MiB
static const size_t W2B_BYTES = (size_t)N_TOT * K_TOT * 2;   //   8 MiB
static const size_t WS_NEED   = H_BYTES + W2B_BYTES;

// swizzle within a 64-byte tile row (4 slots of 16B): slot' = slot ^ ((row>>1)&3)
#define SWZ32(row, bytecol) ((bytecol) ^ ((((row) >> 1) & 3) << 4))

#define GLD16(gp, lp) __builtin_amdgcn_global_load_lds( \
    (const __attribute__((address_space(1))) unsigned int*)(const void*)(gp), \
    (__attribute__((address_space(3))) unsigned int*)(void*)(lp), 16, 0, 0)

static __device__ inline unsigned short f2bf(float f) {
    __hip_bfloat16 b = __float2bfloat16(f);
    unsigned short u;
    __builtin_memcpy(&u, &b, 2);
    return u;
}

// ---------------- pass 1: h and W2 -> bf16 tiled-swizzled (merged) ----------------
// blocks 0..2047: h path (bx = b>>5 m-tile of 256, by = b&31 k-chunk of 128)
// blocks 2048..4095: w2 convert path
__global__ __launch_bounds__(256)
void k_prep(const float* __restrict__ x, const float* __restrict__ theta,
            const float* __restrict__ W1, const float* __restrict__ W2,
            char* __restrict__ hws, char* __restrict__ w2ws)
{
    __shared__ float sZ[256 * 8];
    __shared__ float sW[128 * 8];
    const int tid = threadIdx.x;

    if (blockIdx.x < 2048) {
        const int bx = blockIdx.x >> 5;
        const int by = blockIdx.x & 31;

        {   // z for this block's 256 rows (one row per thread)
            const float* xp = x + ((size_t)bx * 256 + tid) * 1024;
            f32x4 a = *reinterpret_cast<const f32x4*>(xp);
            f32x4 b = *reinterpret_cast<const f32x4*>(xp + 4);
            #pragma unroll
            for (int q = 0; q < 4; ++q) {
                sZ[tid * 8 + q]     = cosf(a[q]) * cosf(theta[q]);
                sZ[tid * 8 + 4 + q] = cosf(b[q]) * cosf(theta[q + 4]);
            }
        }
        *reinterpret_cast<f32x4*>(&sW[tid * 4]) =
            *reinterpret_cast<const f32x4*>(W1 + (size_t)by * 1024 + tid * 4);
        __syncthreads();

        const int tm = tid >> 4;     // rows tm*16..+15
        const int tk = tid & 15;     // k-cols tk*8..+7 (within 128-chunk)

        f32x4 wA[8], wB[8];
        #pragma unroll
        for (int kk = 0; kk < 8; ++kk) {
            wA[kk] = *reinterpret_cast<const f32x4*>(&sW[(tk * 8 + kk) * 8]);
            wB[kk] = *reinterpret_cast<const f32x4*>(&sW[(tk * 8 + kk) * 8 + 4]);
        }

        const int kt    = by * 4 + (tk >> 2);
        const int slotb = (tk & 3) * 16;
        char* tb = hws + ((size_t)bx * NKT + kt) * TILEB;

        #pragma unroll
        for (int i = 0; i < 16; ++i) {
            const int row = tm * 16 + i;
            f32x4 za = *reinterpret_cast<const f32x4*>(&sZ[row * 8]);
            f32x4 zb = *reinterpret_cast<const f32x4*>(&sZ[row * 8 + 4]);
            unsigned hu[8];
            #pragma unroll
            for (int kk = 0; kk < 8; ++kk) {
                float h = 0.f;
                #pragma unroll
                for (int q = 0; q < 4; ++q) {
                    h = fmaf(za[q], wA[kk][q], h);
                    h = fmaf(zb[q], wB[kk][q], h);
                }
                hu[kk] = (unsigned)f2bf(fmaxf(h, 0.f));
            }
            i32x4 pk;
            pk[0] = (int)(hu[0] | (hu[1] << 16));
            pk[1] = (int)(hu[2] | (hu[3] << 16));
            pk[2] = (int)(hu[4] | (hu[5] << 16));
            pk[3] = (int)(hu[6] | (hu[7] << 16));
            *reinterpret_cast<i32x4*>(tb + row * 64 + SWZ32(row, slotb)) = pk;
        }
    } else {
        const int gt = (blockIdx.x - 2048) * 256 + tid;  // one 8-k unit each
        const int n  = gt >> 9;                          // 512 units per n-row
        const int k8 = gt & 511;
        const float* p = W2 + (size_t)n * K_TOT + k8 * 8;
        f32x4 a = *reinterpret_cast<const f32x4*>(p);
        f32x4 b = *reinterpret_cast<const f32x4*>(p + 4);
        i32x4 pk;
        pk[0] = (int)((unsigned)f2bf(a[0]) | ((unsigned)f2bf(a[1]) << 16));
        pk[1] = (int)((unsigned)f2bf(a[2]) | ((unsigned)f2bf(a[3]) << 16));
        pk[2] = (int)((unsigned)f2bf(b[0]) | ((unsigned)f2bf(b[1]) << 16));
        pk[3] = (int)((unsigned)f2bf(b[2]) | ((unsigned)f2bf(b[3]) << 16));
        const int nt = n >> 8, row = n & 255, kt = k8 >> 2, slotb = (k8 & 3) * 16;
        char* dst = w2ws + ((size_t)nt * NKT + kt) * TILEB + row * 64 + SWZ32(row, slotb);
        *reinterpret_cast<i32x4*>(dst) = pk;
    }
}

// ---------------- pass 2: out = h @ W2^T ----------------
// 256x256 block tile, BK=32, 8 waves (2Mx4N, 128x64 per wave), 4-deep LDS ring.
// Register-prefetch pipeline: phase t = {vmcnt(4)+barrier; ds_read frag[t+1] -> P[(t+1)&1];
// GLD stage tile t+3; 32 MFMA on P[t&1]}.

#define DS_FRAGS(RD, BUF1) do {                                                   \
    const char* sa_ = ldsA + (BUF1) * 16384;                                      \
    const char* sb_ = ldsB + (BUF1) * 16384;                                      \
    _Pragma("unroll")                                                             \
    for (int i = 0; i < 8; ++i)                                                   \
        Pa[RD][i] = *reinterpret_cast<const bf16x8*>(sa_ + aoff + i * 1024);      \
    _Pragma("unroll")                                                             \
    for (int j = 0; j < 4; ++j)                                                   \
        Pb[RD][j] = *reinterpret_cast<const bf16x8*>(sb_ + boff + j * 1024);      \
} while (0)

#define STAGE4(KT3, BUF3) do {                                                    \
    const char* ga_ = aT + (size_t)(KT3) * TILEB;                                 \
    const char* gb_ = bT + (size_t)(KT3) * TILEB;                                 \
    GLD16(ga_ + gofs,        ldsA + (BUF3) * 16384 + lofs);                       \
    GLD16(ga_ + 8192 + gofs, ldsA + (BUF3) * 16384 + 8192 + lofs);                \
    GLD16(gb_ + gofs,        ldsB + (BUF3) * 16384 + lofs);                       \
    GLD16(gb_ + 8192 + gofs, ldsB + (BUF3) * 16384 + 8192 + lofs);                \
} while (0)

#define MFMA32(USE) do {                                                          \
    __builtin_amdgcn_s_setprio(1);                                                \
    _Pragma("unroll")                                                             \
    for (int i = 0; i < 8; ++i)                                                   \
        _Pragma("unroll")                                                         \
        for (int j = 0; j < 4; ++j)                                               \
            acc[i][j] = __builtin_amdgcn_mfma_f32_16x16x32_bf16(Pa[USE][i], Pb[USE][j], acc[i][j], 0, 0, 0); \
    __builtin_amdgcn_s_setprio(0);                                                \
} while (0)

#define PHASE(BUF, KT, WN, DOREAD, DOSTAGE) do {                                  \
    asm volatile("s_waitcnt vmcnt(" #WN ")" ::: "memory");                        \
    __builtin_amdgcn_sched_barrier(0);                                            \
    __builtin_amdgcn_s_barrier();                                                 \
    __builtin_amdgcn_sched_barrier(0);                                            \
    if (DOREAD)  DS_FRAGS(((BUF) + 1) & 1, ((BUF) + 1) & 3);                      \
    if (DOSTAGE) STAGE4((KT) + 3, ((BUF) + 3) & 3);                               \
    __builtin_amdgcn_sched_barrier(0);                                            \
    MFMA32((BUF) & 1);                                                            \
} while (0)

__global__ __launch_bounds__(512, 2)
void k_gemm(const char* __restrict__ hws, const char* __restrict__ w2ws,
            float* __restrict__ out)
{
    __shared__ __align__(16) char lds[131072];
    char* const ldsA = lds;
    char* const ldsB = lds + 65536;

    const int tid  = threadIdx.x;
    const int lane = tid & 63;
    const int wave = tid >> 6;
    const int wm = wave >> 2;        // 0..1
    const int wn = wave & 3;         // 0..3
    const int mt = blockIdx.x;       // 0..63
    const int nt = blockIdx.y;       // 0..3

    const char* aT = hws  + (size_t)mt * NKT * TILEB;
    const char* bT = w2ws + (size_t)nt * NKT * TILEB;

    const int l16 = lane & 15;
    const int lkb = (lane >> 4) * 16;
    // frag LDS offsets: +i*1024 / +j*1024 preserves row&7 (16-row step), swizzle-invariant
    const int arow0 = wm * 128 + l16;
    const int aoff  = arow0 * 64 + SWZ32(arow0, lkb);
    const int brow0 = wn * 64 + l16;
    const int boff  = brow0 * 64 + SWZ32(brow0, lkb);

    const int gofs = tid * 16;
    const int lofs = wave * 1024;

    bf16x8 Pa[2][8];
    bf16x8 Pb[2][4];

    f32x4 acc[8][4];
    #pragma unroll
    for (int i = 0; i < 8; ++i)
        #pragma unroll
        for (int j = 0; j < 4; ++j)
            acc[i][j] = {0.f, 0.f, 0.f, 0.f};

    // prologue: stage K-tiles 0,1,2; preload frag[0] into P0
    STAGE4(0, 0);
    STAGE4(1, 1);
    STAGE4(2, 2);
    asm volatile("s_waitcnt vmcnt(8)" ::: "memory");   // tile 0 resident
    __builtin_amdgcn_sched_barrier(0);
    __builtin_amdgcn_s_barrier();
    __builtin_amdgcn_sched_barrier(0);
    DS_FRAGS(0, 0);

    #pragma unroll 1
    for (int t = 0; t < 124; t += 4) {
        PHASE(0, t,     4, 1, 1);
        PHASE(1, t + 1, 4, 1, 1);
        PHASE(2, t + 2, 4, 1, 1);
        PHASE(3, t + 3, 4, 1, 1);
    }
    PHASE(0, 124, 4, 1, 1);   // stages tile 127
    PHASE(1, 125, 4, 1, 0);   // reads frag 126 (tile 126 resident: only 127 outstanding > 4? no: 126,127 -> vmcnt(4) leaves 127)
    PHASE(2, 126, 0, 1, 0);   // reads frag 127 (vmcnt(0): tile 127 resident)
    MFMA32(1);                // phase 127: pure MFMA on P1

    const int orow0 = mt * 256 + wm * 128 + (lane >> 4) * 4;
    const int ocol0 = nt * 256 + wn * 64 + l16;
    #pragma unroll
    for (int i = 0; i < 8; ++i)
        #pragma unroll
        for (int j = 0; j < 4; ++j)
            #pragma unroll
            for (int jj = 0; jj < 4; ++jj)
                out[(size_t)(orow0 + i * 16 + jj) * N_TOT + (ocol0 + j * 16)] = acc[i][j][jj];
}

// ---------------- fallback: fused single kernel (ws too small) ----------------
__global__ __launch_bounds__(256, 3)
void qffn_fused(const float* __restrict__ x, const float* __restrict__ theta,
                const float* __restrict__ W1, const float* __restrict__ W2,
                float* __restrict__ out)
{
    __shared__ __align__(16) unsigned short sA[128 * 64];
    __shared__ __align__(16) unsigned short sB[128 * 64];

    const int tid  = threadIdx.x;
    const int lane = tid & 63;
    const int wave = tid >> 6;
    const int m0 = blockIdx.x * 128;
    const int n0 = blockIdx.y * 128;

    const int arow = tid & 127;
    float zc[8];
    {
        const float* xp = x + (size_t)(m0 + arow) * 1024;
        f32x4 x0 = *reinterpret_cast<const f32x4*>(xp);
        f32x4 x1 = *reinterpret_cast<const f32x4*>(xp + 4);
        #pragma unroll
        for (int q = 0; q < 4; ++q) {
            zc[q]     = cosf(x0[q]) * cosf(theta[q]);
            zc[q + 4] = cosf(x1[q]) * cosf(theta[q + 4]);
        }
    }

    f32x4 acc[4][4];
    #pragma unroll
    for (int i = 0; i < 4; ++i)
        #pragma unroll
        for (int j = 0; j < 4; ++j)
            acc[i][j] = {0.f, 0.f, 0.f, 0.f};

    const int wr  = (wave >> 1) * 64;
    const int wc  = (wave & 1) * 64;
    const int l16 = lane & 15;
    const int lk8 = (lane >> 4) * 8;

    for (int k0 = 0; k0 < K_TOT; k0 += 64) {
        #pragma unroll
        for (int g = 0; g < 4; ++g) {
            const int cg  = (tid >> 7) + 2 * g;
            const int cgu = __builtin_amdgcn_readfirstlane(cg);
            const float* w1p = W1 + (size_t)(k0 + cgu * 8) * 8;
            i32x4 pk;
            #pragma unroll
            for (int p = 0; p < 4; ++p) {
                float h0 = 0.f, h1 = 0.f;
                #pragma unroll
                for (int q = 0; q < 8; ++q) {
                    h0 = fmaf(zc[q], w1p[(2 * p) * 8 + q], h0);
                    h1 = fmaf(zc[q], w1p[(2 * p + 1) * 8 + q], h1);
                }
                pk[p] = (int)(((unsigned)f2bf(fmaxf(h0, 0.f))) |
                              (((unsigned)f2bf(fmaxf(h1, 0.f))) << 16));
            }
            const int off = (arow * 64 + cg * 8) ^ ((arow & 7) << 3);
            *reinterpret_cast<i32x4*>(&sA[off]) = pk;
        }
        {
            const int fi = tid & 15;
            const int rb = tid >> 4;
            #pragma unroll
            for (int r = 0; r < 8; ++r) {
                const int row = rb + r * 16;
                f32x4 v = *(reinterpret_cast<const f32x4*>(W2 + (size_t)(n0 + row) * K_TOT + k0) + fi);
                unsigned p0 = (unsigned)f2bf(v[0]) | ((unsigned)f2bf(v[1]) << 16);
                unsigned p1 = (unsigned)f2bf(v[2]) | ((unsigned)f2bf(v[3]) << 16);
                const int off = (row * 64 + fi * 4) ^ ((row & 7) << 3);
                *reinterpret_cast<unsigned*>(&sB[off])     = p0;
                *reinterpret_cast<unsigned*>(&sB[off + 2]) = p1;
            }
        }
        __syncthreads();

        #pragma unroll
        for (int s = 0; s < 2; ++s) {
            bf16x8 af[4], bfr[4];
            #pragma unroll
            for (int i = 0; i < 4; ++i) {
                const int row = wr + i * 16 + l16;
                const int off = (row * 64 + s * 32 + lk8) ^ ((row & 7) << 3);
                af[i] = *reinterpret_cast<const bf16x8*>(&sA[off]);
            }
            #pragma unroll
            for (int j = 0; j < 4; ++j) {
                const int row = wc + j * 16 + l16;
                const int off = (row * 64 + s * 32 + lk8) ^ ((row & 7) << 3);
                bfr[j] = *reinterpret_cast<const bf16x8*>(&sB[off]);
            }
            #pragma unroll
            for (int i = 0; i < 4; ++i)
                #pragma unroll
                for (int j = 0; j < 4; ++j)
                    acc[i][j] = __builtin_amdgcn_mfma_f32_16x16x32_bf16(af[i], bfr[j], acc[i][j], 0, 0, 0);
        }
        __syncthreads();
    }

    const int orow0 = m0 + wr + (lane >> 4) * 4;
    const int ocol0 = n0 + wc + l16;
    #pragma unroll
    for (int i = 0; i < 4; ++i)
        #pragma unroll
        for (int j = 0; j < 4; ++j)
            #pragma unroll
            for (int jj = 0; jj < 4; ++jj)
                out[(size_t)(orow0 + i * 16 + jj) * N_TOT + (ocol0 + j * 16)] = acc[i][j][jj];
}

extern "C" void kernel_launch(void* const* d_in, const int* in_sizes, int n_in,
                              void* d_out, int out_size, void* d_ws, size_t ws_size,
                              hipStream_t stream) {
    const float* x     = (const float*)d_in[0];
    const float* theta = (const float*)d_in[1];
    const float* W1    = (const float*)d_in[2];
    const float* W2    = (const float*)d_in[3];
    float* out = (float*)d_out;

    if (ws_size >= WS_NEED) {
        char* hws  = (char*)d_ws;
        char* w2ws = (char*)d_ws + H_BYTES;

        k_prep<<<dim3(4096), dim3(256), 0, stream>>>(x, theta, W1, W2, hws, w2ws);
        k_gemm<<<dim3(M_TOT / 256, N_TOT / 256), dim3(512), 0, stream>>>(hws, w2ws, out);
    } else {
        qffn_fused<<<dim3(M_TOT / 128, N_TOT / 128), dim3(256), 0, stream>>>(x, theta, W1, W2, out);
    }
}